// Round 2
// baseline (651.585 us; speedup 1.0000x reference)
//
#include <hip/hip_runtime.h>
#include <cstdint>
#include <cstddef>

// GCN link prediction: 3x GCNConv(64->64) + ReLU, then 2-layer MLP head.
// N=100k nodes, E=1M edges. Strategy:
//   1. Build CSR (edges grouped by dst) once per launch via counting sort.
//      Pack (src, norm=dinv[src]*dinv[dst]) as int2 per edge.
//   2. Per layer: mm64 (wave-per-row, W column in 64 VGPRs, readlane
//      broadcast) then agg (wave-per-node, lane=feature, coalesced row
//      gathers, no atomics).
// All fp32 — no fp32 MFMA on CDNA4 and bf16 is risky vs 1.28e-2 threshold.
// NOTE: harness passes integer inputs as int32 (edge_index is int*, 2E elems).
// d_out doubles as a ping-pong activation buffer to keep ws usage ~35 MB.

#define CDIV(a, b) (((a) + (b) - 1) / (b))
static constexpr int SCAN_B = 1024;

__global__ void k_zero_i32(int* __restrict__ p, int n) {
  int i = blockIdx.x * blockDim.x + threadIdx.x;
  if (i < n) p[i] = 0;
}

__global__ void k_count(const int* __restrict__ ei, int* __restrict__ counts, int E) {
  int e = blockIdx.x * blockDim.x + threadIdx.x;
  if (e < E) atomicAdd(&counts[ei[E + e]], 1);
}

__global__ void k_dinv(const int* __restrict__ counts, float* __restrict__ dinv, int n) {
  int i = blockIdx.x * blockDim.x + threadIdx.x;
  if (i < n) dinv[i] = rsqrtf((float)counts[i] + 1.0f);
}

// Inclusive block scan (Hillis-Steele) -> exclusive output + per-block sums.
__global__ void k_scan1(const int* __restrict__ counts, int* __restrict__ excl,
                        int* __restrict__ bsums, int n) {
  __shared__ int sh[SCAN_B];
  int t = threadIdx.x;
  int idx = blockIdx.x * SCAN_B + t;
  int v = (idx < n) ? counts[idx] : 0;
  int val = v;
  sh[t] = val;
  __syncthreads();
  for (int off = 1; off < SCAN_B; off <<= 1) {
    int add = (t >= off) ? sh[t - off] : 0;
    __syncthreads();
    val += add;
    sh[t] = val;
    __syncthreads();
  }
  if (idx < n) excl[idx] = val - v;
  if (t == SCAN_B - 1) bsums[blockIdx.x] = val;
}

// Exclusive scan of the (<=1024) block sums, single block.
__global__ void k_scan2(int* __restrict__ bsums, int nb) {
  __shared__ int sh[SCAN_B];
  int t = threadIdx.x;
  int v = (t < nb) ? bsums[t] : 0;
  int val = v;
  sh[t] = val;
  __syncthreads();
  for (int off = 1; off < SCAN_B; off <<= 1) {
    int add = (t >= off) ? sh[t - off] : 0;
    __syncthreads();
    val += add;
    sh[t] = val;
    __syncthreads();
  }
  if (t < nb) bsums[t] = val - v;
}

__global__ void k_scan3(int* __restrict__ row_ptr, const int* __restrict__ bsums,
                        int* __restrict__ counts, int n, int E) {
  int i = blockIdx.x * blockDim.x + threadIdx.x;
  if (i < n) {
    row_ptr[i] += bsums[i >> 10];  // SCAN_B == 1024
    counts[i] = 0;                 // reuse as fill cursors
  }
  if (i == 0) row_ptr[n] = E;
}

__global__ void k_fill(const int* __restrict__ ei, const float* __restrict__ dinv,
                       const int* __restrict__ row_ptr, int* __restrict__ counts,
                       int2* __restrict__ cn, int E) {
  int e = blockIdx.x * blockDim.x + threadIdx.x;
  if (e >= E) return;
  int s = ei[e];
  int d = ei[E + e];
  int pos = row_ptr[d] + atomicAdd(&counts[d], 1);
  cn[pos] = make_int2(s, __float_as_int(dinv[s] * dinv[d]));
}

// out[row, lane] = sum_k act(in[row,k]) * W[k,lane] (+bias) (+relu)
// W stored [in, out] row-major => W[k*64 + lane]. One wave per row; lane j
// holds W[:,j] in 64 VGPRs; input element k broadcast via v_readlane (SGPR
// operand into v_fmac). Safe for in==out (row read before row write).
template <bool RELU_IN, bool RELU_OUT, bool HAS_BIAS>
__global__ void k_mm64(const float* __restrict__ in, const float* __restrict__ W,
                       const float* __restrict__ bias, float* __restrict__ out, int n) {
  int lane = threadIdx.x & 63;
  int wid = (blockIdx.x * blockDim.x + threadIdx.x) >> 6;
  int nwaves = (gridDim.x * blockDim.x) >> 6;
  float wreg[64];
#pragma unroll
  for (int k = 0; k < 64; ++k) wreg[k] = W[k * 64 + lane];
  float bv = HAS_BIAS ? bias[lane] : 0.0f;
  for (int row = wid; row < n; row += nwaves) {
    float a = in[(size_t)row * 64 + lane];
    if (RELU_IN) a = fmaxf(a, 0.0f);
    float acc = bv;
#pragma unroll
    for (int k = 0; k < 64; ++k) {
      float s = __int_as_float(__builtin_amdgcn_readlane(__float_as_int(a), k));
      acc = fmaf(s, wreg[k], acc);
    }
    if (RELU_OUT) acc = fmaxf(acc, 0.0f);
    out[(size_t)row * 64 + lane] = acc;
  }
}

// One wave per node, lane = feature. agg[n] = sum_{e:dst=n} hw[src_e]*norm_e
//                                           + hw[n]*dinv[n]^2 + bias
__global__ void k_agg(const float* __restrict__ hw, const float* __restrict__ dinv,
                      const int* __restrict__ row_ptr, const int2* __restrict__ cn,
                      const float* __restrict__ bias, float* __restrict__ out, int n) {
  int gid = blockIdx.x * blockDim.x + threadIdx.x;
  int node = gid >> 6;
  if (node >= n) return;
  int lane = gid & 63;
  float di = dinv[node];
  float acc = fmaf(hw[(size_t)node * 64 + lane], di * di, bias[lane]);
  int p0 = row_ptr[node], p1 = row_ptr[node + 1];
  for (int p = p0; p < p1; ++p) {
    int2 e = cn[p];
    acc = fmaf(hw[(size_t)e.x * 64 + lane], __int_as_float(e.y), acc);
  }
  out[(size_t)node * 64 + lane] = acc;
}

extern "C" void kernel_launch(void* const* d_in, const int* in_sizes, int n_in,
                              void* d_out, int out_size, void* d_ws, size_t ws_size,
                              hipStream_t stream) {
  const float* x = (const float*)d_in[0];
  const int* ei = (const int*)d_in[1];  // int32 per harness convention
  const float* W1 = (const float*)d_in[2];
  const float* b1 = (const float*)d_in[3];
  const float* W2 = (const float*)d_in[4];
  const float* b2 = (const float*)d_in[5];
  const float* W3 = (const float*)d_in[6];
  const float* b3 = (const float*)d_in[7];
  const float* fw1 = (const float*)d_in[8];
  const float* fb1 = (const float*)d_in[9];
  const float* fw2 = (const float*)d_in[10];
  const float* fb2 = (const float*)d_in[11];
  float* out = (float*)d_out;

  const int N = in_sizes[0] / 64;
  const int E = in_sizes[1] / 2;

  // workspace carve-up (~35 MB total); d_out is the second activation buffer
  char* w = (char*)d_ws;
  auto take = [&](size_t bytes) -> char* {
    char* p = w;
    w += (bytes + 255) & ~(size_t)255;
    return p;
  };
  float* dinv = (float*)take((size_t)N * 4);
  int* counts = (int*)take((size_t)N * 4);
  int* row_ptr = (int*)take((size_t)(N + 1) * 4);
  int* bsums = (int*)take((size_t)SCAN_B * 4);
  int2* cn = (int2*)take((size_t)E * 8);
  float* buf0 = (float*)take((size_t)N * 64 * 4);
  float* buf1 = out;  // alias d_out as ping-pong buffer (rewritten at the end)

  const int B = 256;
  const int nb_scan = CDIV(N, SCAN_B);

  // ---- CSR build + degrees ----
  k_zero_i32<<<CDIV(N, B), B, 0, stream>>>(counts, N);
  k_count<<<CDIV(E, B), B, 0, stream>>>(ei, counts, E);
  k_dinv<<<CDIV(N, B), B, 0, stream>>>(counts, dinv, N);
  k_scan1<<<nb_scan, SCAN_B, 0, stream>>>(counts, row_ptr, bsums, N);
  k_scan2<<<1, SCAN_B, 0, stream>>>(bsums, nb_scan);
  k_scan3<<<CDIV(N, B), B, 0, stream>>>(row_ptr, bsums, counts, N, E);
  k_fill<<<CDIV(E, B), B, 0, stream>>>(ei, dinv, row_ptr, counts, cn, E);

  const int MMG = 4096;  // 16384 waves, ~6 rows each
  const int AGG_G = CDIV(N * 64, B);

  // ---- layer 1: mm x->buf0, agg buf0->buf1 ----
  k_mm64<false, false, false><<<MMG, B, 0, stream>>>(x, W1, nullptr, buf0, N);
  k_agg<<<AGG_G, B, 0, stream>>>(buf0, dinv, row_ptr, cn, b1, buf1, N);
  // ---- layer 2: mm buf1->buf0 (relu on load), agg buf0->buf1 ----
  k_mm64<true, false, false><<<MMG, B, 0, stream>>>(buf1, W2, nullptr, buf0, N);
  k_agg<<<AGG_G, B, 0, stream>>>(buf0, dinv, row_ptr, cn, b2, buf1, N);
  // ---- layer 3 ----
  k_mm64<true, false, false><<<MMG, B, 0, stream>>>(buf1, W3, nullptr, buf0, N);
  k_agg<<<AGG_G, B, 0, stream>>>(buf0, dinv, row_ptr, cn, b3, buf1, N);
  // ---- MLP head: mm buf1->buf0 (+bias+relu), mm buf0->out (+bias) ----
  k_mm64<true, true, true><<<MMG, B, 0, stream>>>(buf1, fw1, fb1, buf0, N);
  k_mm64<false, false, true><<<MMG, B, 0, stream>>>(buf0, fw2, fb2, out, N);
}

// Round 3
// 508.951 us; speedup vs baseline: 1.2803x; 1.2803x over previous
//
#include <hip/hip_runtime.h>
#include <cstdint>
#include <cstddef>

// GCN link prediction: 3x GCNConv(64->64) + ReLU, then 2-layer MLP head.
// N=100k, E=1M, all dims 64, fp32 throughout (threshold 1.28e-2; fp32 gives 5e-4).
// CSR built per launch (counting sort), edges packed as int2{src, norm}.
// Round 3: k_agg uses 4 edge-slots x 16 lanes x float4 (4 gathers in flight);
// k_mm64 processes 2 rows/wave (2 independent fmac chains to hide the
// v_readlane->SGPR->v_fmac hazard).

#define CDIV(a, b) (((a) + (b) - 1) / (b))
static constexpr int SCAN_B = 1024;

__global__ void k_zero_i32(int* __restrict__ p, int n) {
  int i = blockIdx.x * blockDim.x + threadIdx.x;
  if (i < n) p[i] = 0;
}

__global__ void k_count(const int* __restrict__ ei, int* __restrict__ counts, int E) {
  int e = blockIdx.x * blockDim.x + threadIdx.x;
  if (e < E) atomicAdd(&counts[ei[E + e]], 1);
}

__global__ void k_dinv(const int* __restrict__ counts, float* __restrict__ dinv, int n) {
  int i = blockIdx.x * blockDim.x + threadIdx.x;
  if (i < n) dinv[i] = rsqrtf((float)counts[i] + 1.0f);
}

// Inclusive block scan (Hillis-Steele) -> exclusive output + per-block sums.
__global__ void k_scan1(const int* __restrict__ counts, int* __restrict__ excl,
                        int* __restrict__ bsums, int n) {
  __shared__ int sh[SCAN_B];
  int t = threadIdx.x;
  int idx = blockIdx.x * SCAN_B + t;
  int v = (idx < n) ? counts[idx] : 0;
  int val = v;
  sh[t] = val;
  __syncthreads();
  for (int off = 1; off < SCAN_B; off <<= 1) {
    int add = (t >= off) ? sh[t - off] : 0;
    __syncthreads();
    val += add;
    sh[t] = val;
    __syncthreads();
  }
  if (idx < n) excl[idx] = val - v;
  if (t == SCAN_B - 1) bsums[blockIdx.x] = val;
}

__global__ void k_scan2(int* __restrict__ bsums, int nb) {
  __shared__ int sh[SCAN_B];
  int t = threadIdx.x;
  int v = (t < nb) ? bsums[t] : 0;
  int val = v;
  sh[t] = val;
  __syncthreads();
  for (int off = 1; off < SCAN_B; off <<= 1) {
    int add = (t >= off) ? sh[t - off] : 0;
    __syncthreads();
    val += add;
    sh[t] = val;
    __syncthreads();
  }
  if (t < nb) bsums[t] = val - v;
}

__global__ void k_scan3(int* __restrict__ row_ptr, const int* __restrict__ bsums,
                        int* __restrict__ counts, int n, int E) {
  int i = blockIdx.x * blockDim.x + threadIdx.x;
  if (i < n) {
    row_ptr[i] += bsums[i >> 10];  // SCAN_B == 1024
    counts[i] = 0;                 // reuse as fill cursors
  }
  if (i == 0) row_ptr[n] = E;
}

__global__ void k_fill(const int* __restrict__ ei, const float* __restrict__ dinv,
                       const int* __restrict__ row_ptr, int* __restrict__ counts,
                       int2* __restrict__ cn, int E) {
  int e = blockIdx.x * blockDim.x + threadIdx.x;
  if (e >= E) return;
  int s = ei[e];
  int d = ei[E + e];
  int pos = row_ptr[d] + atomicAdd(&counts[d], 1);
  cn[pos] = make_int2(s, __float_as_int(dinv[s] * dinv[d]));
}

// out[row, lane] = sum_k act(in[row,k]) * W[k,lane] (+bias) (+relu)
// Two rows per wave: two independent fmac chains interleave so the
// v_readlane->SGPR hazard slots are filled by the other row's work.
template <bool RELU_IN, bool RELU_OUT, bool HAS_BIAS>
__global__ void k_mm64(const float* __restrict__ in, const float* __restrict__ W,
                       const float* __restrict__ bias, float* __restrict__ out, int n) {
  int lane = threadIdx.x & 63;
  int wid = (blockIdx.x * blockDim.x + threadIdx.x) >> 6;
  float wreg[64];
#pragma unroll
  for (int k = 0; k < 64; ++k) wreg[k] = W[k * 64 + lane];
  float bv = HAS_BIAS ? bias[lane] : 0.0f;

  int row0 = wid * 2;
  if (row0 >= n) return;
  bool have1 = (row0 + 1) < n;
  float a0 = in[(size_t)row0 * 64 + lane];
  float a1 = have1 ? in[(size_t)(row0 + 1) * 64 + lane] : 0.0f;
  if (RELU_IN) { a0 = fmaxf(a0, 0.0f); a1 = fmaxf(a1, 0.0f); }
  float acc0 = bv, acc1 = bv;
#pragma unroll
  for (int k = 0; k < 64; ++k) {
    float s0 = __int_as_float(__builtin_amdgcn_readlane(__float_as_int(a0), k));
    float s1 = __int_as_float(__builtin_amdgcn_readlane(__float_as_int(a1), k));
    acc0 = fmaf(s0, wreg[k], acc0);
    acc1 = fmaf(s1, wreg[k], acc1);
  }
  if (RELU_OUT) { acc0 = fmaxf(acc0, 0.0f); acc1 = fmaxf(acc1, 0.0f); }
  out[(size_t)row0 * 64 + lane] = acc0;
  if (have1) out[(size_t)(row0 + 1) * 64 + lane] = acc1;
}

// One wave per node; 4 edge-slots x 16 lanes x float4.
// Slot s handles edges p0+s, p0+s+4, ...; 4 independent 256 B row gathers
// in flight per wave. Cross-slot butterfly reduce (xor 16, 32), slot 0 adds
// the self-loop term + bias and writes the float4 row.
__global__ void k_agg(const float* __restrict__ hw, const float* __restrict__ dinv,
                      const int* __restrict__ row_ptr, const int2* __restrict__ cn,
                      const float* __restrict__ bias, float* __restrict__ out, int n) {
  int wid = (blockIdx.x * blockDim.x + threadIdx.x) >> 6;
  if (wid >= n) return;
  int lane = threadIdx.x & 63;
  int slot = lane >> 4;  // 0..3
  int fg = lane & 15;    // float4 feature group
  const float4* hw4 = (const float4*)hw;

  int p0 = row_ptr[wid], p1 = row_ptr[wid + 1];
  float4 acc = make_float4(0.f, 0.f, 0.f, 0.f);
  for (int p = p0 + slot; p < p1; p += 4) {
    int2 e = cn[p];
    float nrm = __int_as_float(e.y);
    float4 v = hw4[(size_t)e.x * 16 + fg];
    acc.x = fmaf(v.x, nrm, acc.x);
    acc.y = fmaf(v.y, nrm, acc.y);
    acc.z = fmaf(v.z, nrm, acc.z);
    acc.w = fmaf(v.w, nrm, acc.w);
  }
#pragma unroll
  for (int off = 16; off < 64; off <<= 1) {
    acc.x += __shfl_xor(acc.x, off);
    acc.y += __shfl_xor(acc.y, off);
    acc.z += __shfl_xor(acc.z, off);
    acc.w += __shfl_xor(acc.w, off);
  }
  if (slot == 0) {
    float di = dinv[wid];
    float d2 = di * di;
    float4 self = hw4[(size_t)wid * 16 + fg];
    float4 b4 = ((const float4*)bias)[fg];
    float4 r;
    r.x = fmaf(self.x, d2, acc.x + b4.x);
    r.y = fmaf(self.y, d2, acc.y + b4.y);
    r.z = fmaf(self.z, d2, acc.z + b4.z);
    r.w = fmaf(self.w, d2, acc.w + b4.w);
    ((float4*)out)[(size_t)wid * 16 + fg] = r;
  }
}

extern "C" void kernel_launch(void* const* d_in, const int* in_sizes, int n_in,
                              void* d_out, int out_size, void* d_ws, size_t ws_size,
                              hipStream_t stream) {
  const float* x = (const float*)d_in[0];
  const int* ei = (const int*)d_in[1];  // int32 per harness convention
  const float* W1 = (const float*)d_in[2];
  const float* b1 = (const float*)d_in[3];
  const float* W2 = (const float*)d_in[4];
  const float* b2 = (const float*)d_in[5];
  const float* W3 = (const float*)d_in[6];
  const float* b3 = (const float*)d_in[7];
  const float* fw1 = (const float*)d_in[8];
  const float* fb1 = (const float*)d_in[9];
  const float* fw2 = (const float*)d_in[10];
  const float* fb2 = (const float*)d_in[11];
  float* out = (float*)d_out;

  const int N = in_sizes[0] / 64;
  const int E = in_sizes[1] / 2;

  // workspace carve-up (~35 MB); d_out is the second activation buffer
  char* w = (char*)d_ws;
  auto take = [&](size_t bytes) -> char* {
    char* p = w;
    w += (bytes + 255) & ~(size_t)255;
    return p;
  };
  float* dinv = (float*)take((size_t)N * 4);
  int* counts = (int*)take((size_t)N * 4);
  int* row_ptr = (int*)take((size_t)(N + 1) * 4);
  int* bsums = (int*)take((size_t)SCAN_B * 4);
  int2* cn = (int2*)take((size_t)E * 8);
  float* buf0 = (float*)take((size_t)N * 64 * 4);
  float* buf1 = out;  // alias d_out as ping-pong buffer (rewritten at the end)

  const int B = 256;
  const int nb_scan = CDIV(N, SCAN_B);

  // ---- CSR build + degrees ----
  k_zero_i32<<<CDIV(N, B), B, 0, stream>>>(counts, N);
  k_count<<<CDIV(E, B), B, 0, stream>>>(ei, counts, E);
  k_dinv<<<CDIV(N, B), B, 0, stream>>>(counts, dinv, N);
  k_scan1<<<nb_scan, SCAN_B, 0, stream>>>(counts, row_ptr, bsums, N);
  k_scan2<<<1, SCAN_B, 0, stream>>>(bsums, nb_scan);
  k_scan3<<<CDIV(N, B), B, 0, stream>>>(row_ptr, bsums, counts, N, E);
  k_fill<<<CDIV(E, B), B, 0, stream>>>(ei, dinv, row_ptr, counts, cn, E);

  const int MMG = CDIV(N, 8);   // 4 waves/block x 2 rows/wave
  const int AGG_G = CDIV(N, 4); // 4 waves/block x 1 node/wave

  // ---- layer 1: mm x->buf0, agg buf0->buf1 ----
  k_mm64<false, false, false><<<MMG, B, 0, stream>>>(x, W1, nullptr, buf0, N);
  k_agg<<<AGG_G, B, 0, stream>>>(buf0, dinv, row_ptr, cn, b1, buf1, N);
  // ---- layer 2: mm buf1->buf0 (relu on load), agg buf0->buf1 ----
  k_mm64<true, false, false><<<MMG, B, 0, stream>>>(buf1, W2, nullptr, buf0, N);
  k_agg<<<AGG_G, B, 0, stream>>>(buf0, dinv, row_ptr, cn, b2, buf1, N);
  // ---- layer 3 ----
  k_mm64<true, false, false><<<MMG, B, 0, stream>>>(buf1, W3, nullptr, buf0, N);
  k_agg<<<AGG_G, B, 0, stream>>>(buf0, dinv, row_ptr, cn, b3, buf1, N);
  // ---- MLP head: mm buf1->buf0 (+bias+relu), mm buf0->out (+bias) ----
  k_mm64<true, true, true><<<MMG, B, 0, stream>>>(buf1, fw1, fb1, buf0, N);
  k_mm64<false, false, true><<<MMG, B, 0, stream>>>(buf0, fw2, fb2, out, N);
}

// Round 4
// 414.325 us; speedup vs baseline: 1.5726x; 1.2284x over previous
//
#include <hip/hip_runtime.h>
#include <cstdint>
#include <cstddef>

// GCN link prediction: 3x GCNConv(64->64) + ReLU, then 2-layer MLP head.
// N=100k, E=1M, dims 64. CSR built per launch; edges packed int2{src,norm}.
// Round 4: matmuls via split-bf16 MFMA (A=Ahi+Alo, W=Whi+Wlo; hi*hi+hi*lo+lo*hi
// in fp32 accumulators -> ~2^-16 relative error, threshold is 1.28e-2).
// ReLU folded into producer epilogues (agg / mm RELU_OUT).

#define CDIV(a, b) (((a) + (b) - 1) / (b))
static constexpr int SCAN_B = 1024;

typedef __attribute__((ext_vector_type(8))) short bf16x8;
typedef __attribute__((ext_vector_type(4))) float f32x4;

__device__ __forceinline__ short f2bf(float f) {  // RNE, no NaN handling
  unsigned u = __float_as_uint(f);
  u += 0x7FFF + ((u >> 16) & 1);
  return (short)(u >> 16);
}
__device__ __forceinline__ float bf2f(short s) {
  return __uint_as_float(((unsigned)(unsigned short)s) << 16);
}

__global__ void k_zero_i32(int* __restrict__ p, int n) {
  int i = blockIdx.x * blockDim.x + threadIdx.x;
  if (i < n) p[i] = 0;
}

__global__ void k_count(const int* __restrict__ ei, int* __restrict__ counts, int E) {
  int e = blockIdx.x * blockDim.x + threadIdx.x;
  if (e < E) atomicAdd(&counts[ei[E + e]], 1);
}

__global__ void k_dinv(const int* __restrict__ counts, float* __restrict__ dinv, int n) {
  int i = blockIdx.x * blockDim.x + threadIdx.x;
  if (i < n) dinv[i] = rsqrtf((float)counts[i] + 1.0f);
}

// Inclusive block scan (Hillis-Steele) -> exclusive output + per-block sums.
__global__ void k_scan1(const int* __restrict__ counts, int* __restrict__ excl,
                        int* __restrict__ bsums, int n) {
  __shared__ int sh[SCAN_B];
  int t = threadIdx.x;
  int idx = blockIdx.x * SCAN_B + t;
  int v = (idx < n) ? counts[idx] : 0;
  int val = v;
  sh[t] = val;
  __syncthreads();
  for (int off = 1; off < SCAN_B; off <<= 1) {
    int add = (t >= off) ? sh[t - off] : 0;
    __syncthreads();
    val += add;
    sh[t] = val;
    __syncthreads();
  }
  if (idx < n) excl[idx] = val - v;
  if (t == SCAN_B - 1) bsums[blockIdx.x] = val;
}

__global__ void k_scan2(int* __restrict__ bsums, int nb) {
  __shared__ int sh[SCAN_B];
  int t = threadIdx.x;
  int v = (t < nb) ? bsums[t] : 0;
  int val = v;
  sh[t] = val;
  __syncthreads();
  for (int off = 1; off < SCAN_B; off <<= 1) {
    int add = (t >= off) ? sh[t - off] : 0;
    __syncthreads();
    val += add;
    sh[t] = val;
    __syncthreads();
  }
  if (t < nb) bsums[t] = val - v;
}

__global__ void k_scan3(int* __restrict__ row_ptr, const int* __restrict__ bsums,
                        int* __restrict__ counts, int n, int E) {
  int i = blockIdx.x * blockDim.x + threadIdx.x;
  if (i < n) {
    row_ptr[i] += bsums[i >> 10];  // SCAN_B == 1024
    counts[i] = 0;                 // reuse as fill cursors
  }
  if (i == 0) row_ptr[n] = E;
}

__global__ void k_fill(const int* __restrict__ ei, const float* __restrict__ dinv,
                       const int* __restrict__ row_ptr, int* __restrict__ counts,
                       int2* __restrict__ cn, int E) {
  int e = blockIdx.x * blockDim.x + threadIdx.x;
  if (e >= E) return;
  int s = ei[e];
  int d = ei[E + e];
  int pos = row_ptr[d] + atomicAdd(&counts[d], 1);
  cn[pos] = make_int2(s, __float_as_int(dinv[s] * dinv[d]));
}

// C[n x 64] = A[n x 64] @ W[64 x 64] (+bias) (+relu) via split-bf16 MFMA.
// One wave per 16-row tile, grid-stride. Layouts (m89/m120-verified):
//   A frag: A[m=lane&15][k=quad*8+j] (quad=lane>>4), k-tiles of 32.
//   B frag: B[k=quad*8+j][n=lane&15]
//   C frag: col=lane&15, row=quad*4+reg
template <bool RELU_OUT, bool HAS_BIAS>
__global__ void k_mm_mfma(const float* __restrict__ in, const float* __restrict__ W,
                          const float* __restrict__ bias, float* __restrict__ out, int n) {
  int lane = threadIdx.x & 63;
  int col = lane & 15, quad = lane >> 4;
  int wid = (blockIdx.x * blockDim.x + threadIdx.x) >> 6;
  int nw = (gridDim.x * blockDim.x) >> 6;
  int ntiles = (n + 15) >> 4;

  // W fragments: 4 col-tiles x 2 k-tiles, hi+lo
  bf16x8 wh[4][2], wl[4][2];
#pragma unroll
  for (int t = 0; t < 4; ++t)
#pragma unroll
    for (int q = 0; q < 2; ++q)
#pragma unroll
      for (int j = 0; j < 8; ++j) {
        int k = q * 32 + quad * 8 + j;
        float w = W[k * 64 + t * 16 + col];
        short hi = f2bf(w);
        wh[t][q][j] = hi;
        wl[t][q][j] = f2bf(w - bf2f(hi));
      }
  float bv[4];
#pragma unroll
  for (int t = 0; t < 4; ++t) bv[t] = HAS_BIAS ? bias[t * 16 + col] : 0.0f;

  for (int tile = wid; tile < ntiles; tile += nw) {
    int row0 = tile << 4;
    int ar = row0 + col;
    if (ar > n - 1) ar = n - 1;  // clamp (tail tile); stores are guarded
    const float* arow = in + (size_t)ar * 64 + quad * 8;
    bf16x8 ah[2], al[2];
#pragma unroll
    for (int q = 0; q < 2; ++q) {
#pragma unroll
      for (int j = 0; j < 8; ++j) {
        float a = arow[q * 32 + j];
        short hi = f2bf(a);
        ah[q][j] = hi;
        al[q][j] = f2bf(a - bf2f(hi));
      }
    }
    f32x4 acc[4];
#pragma unroll
    for (int t = 0; t < 4; ++t) acc[t] = (f32x4){0.f, 0.f, 0.f, 0.f};
#pragma unroll
    for (int t = 0; t < 4; ++t)
#pragma unroll
      for (int q = 0; q < 2; ++q) {
        acc[t] = __builtin_amdgcn_mfma_f32_16x16x32_bf16(ah[q], wh[t][q], acc[t], 0, 0, 0);
        acc[t] = __builtin_amdgcn_mfma_f32_16x16x32_bf16(ah[q], wl[t][q], acc[t], 0, 0, 0);
        acc[t] = __builtin_amdgcn_mfma_f32_16x16x32_bf16(al[q], wh[t][q], acc[t], 0, 0, 0);
      }
#pragma unroll
    for (int t = 0; t < 4; ++t)
#pragma unroll
      for (int r = 0; r < 4; ++r) {
        int row = row0 + quad * 4 + r;
        if (row < n) {
          float v = acc[t][r] + bv[t];
          if (RELU_OUT) v = fmaxf(v, 0.0f);
          out[(size_t)row * 64 + t * 16 + col] = v;
        }
      }
  }
}

// One wave per node; 4 edge-slots x 16 lanes x float4.
template <bool RELU>
__global__ void k_agg(const float* __restrict__ hw, const float* __restrict__ dinv,
                      const int* __restrict__ row_ptr, const int2* __restrict__ cn,
                      const float* __restrict__ bias, float* __restrict__ out, int n) {
  int wid = (blockIdx.x * blockDim.x + threadIdx.x) >> 6;
  if (wid >= n) return;
  int lane = threadIdx.x & 63;
  int slot = lane >> 4;  // 0..3
  int fg = lane & 15;    // float4 feature group
  const float4* hw4 = (const float4*)hw;

  int p0 = row_ptr[wid], p1 = row_ptr[wid + 1];
  float4 acc = make_float4(0.f, 0.f, 0.f, 0.f);
  for (int p = p0 + slot; p < p1; p += 4) {
    int2 e = cn[p];
    float nrm = __int_as_float(e.y);
    float4 v = hw4[(size_t)e.x * 16 + fg];
    acc.x = fmaf(v.x, nrm, acc.x);
    acc.y = fmaf(v.y, nrm, acc.y);
    acc.z = fmaf(v.z, nrm, acc.z);
    acc.w = fmaf(v.w, nrm, acc.w);
  }
#pragma unroll
  for (int off = 16; off < 64; off <<= 1) {
    acc.x += __shfl_xor(acc.x, off);
    acc.y += __shfl_xor(acc.y, off);
    acc.z += __shfl_xor(acc.z, off);
    acc.w += __shfl_xor(acc.w, off);
  }
  if (slot == 0) {
    float di = dinv[wid];
    float d2 = di * di;
    float4 self = hw4[(size_t)wid * 16 + fg];
    float4 b4 = ((const float4*)bias)[fg];
    float4 r;
    r.x = fmaf(self.x, d2, acc.x + b4.x);
    r.y = fmaf(self.y, d2, acc.y + b4.y);
    r.z = fmaf(self.z, d2, acc.z + b4.z);
    r.w = fmaf(self.w, d2, acc.w + b4.w);
    if (RELU) {
      r.x = fmaxf(r.x, 0.f); r.y = fmaxf(r.y, 0.f);
      r.z = fmaxf(r.z, 0.f); r.w = fmaxf(r.w, 0.f);
    }
    ((float4*)out)[(size_t)wid * 16 + fg] = r;
  }
}

extern "C" void kernel_launch(void* const* d_in, const int* in_sizes, int n_in,
                              void* d_out, int out_size, void* d_ws, size_t ws_size,
                              hipStream_t stream) {
  const float* x = (const float*)d_in[0];
  const int* ei = (const int*)d_in[1];  // int32 per harness convention
  const float* W1 = (const float*)d_in[2];
  const float* b1 = (const float*)d_in[3];
  const float* W2 = (const float*)d_in[4];
  const float* b2 = (const float*)d_in[5];
  const float* W3 = (const float*)d_in[6];
  const float* b3 = (const float*)d_in[7];
  const float* fw1 = (const float*)d_in[8];
  const float* fb1 = (const float*)d_in[9];
  const float* fw2 = (const float*)d_in[10];
  const float* fb2 = (const float*)d_in[11];
  float* out = (float*)d_out;

  const int N = in_sizes[0] / 64;
  const int E = in_sizes[1] / 2;

  // workspace carve-up (~35 MB); d_out is the second activation buffer
  char* w = (char*)d_ws;
  auto take = [&](size_t bytes) -> char* {
    char* p = w;
    w += (bytes + 255) & ~(size_t)255;
    return p;
  };
  float* dinv = (float*)take((size_t)N * 4);
  int* counts = (int*)take((size_t)N * 4);
  int* row_ptr = (int*)take((size_t)(N + 1) * 4);
  int* bsums = (int*)take((size_t)SCAN_B * 4);
  int2* cn = (int2*)take((size_t)E * 8);
  float* buf0 = (float*)take((size_t)N * 64 * 4);
  float* buf1 = out;  // alias d_out as ping-pong buffer (rewritten at the end)

  const int B = 256;
  const int nb_scan = CDIV(N, SCAN_B);

  // ---- CSR build + degrees ----
  k_zero_i32<<<CDIV(N, B), B, 0, stream>>>(counts, N);
  k_count<<<CDIV(E, B), B, 0, stream>>>(ei, counts, E);
  k_dinv<<<CDIV(N, B), B, 0, stream>>>(counts, dinv, N);
  k_scan1<<<nb_scan, SCAN_B, 0, stream>>>(counts, row_ptr, bsums, N);
  k_scan2<<<1, SCAN_B, 0, stream>>>(bsums, nb_scan);
  k_scan3<<<CDIV(N, B), B, 0, stream>>>(row_ptr, bsums, counts, N, E);
  k_fill<<<CDIV(E, B), B, 0, stream>>>(ei, dinv, row_ptr, counts, cn, E);

  const int MMG = 512;          // 2048 waves, ~3 row-tiles each
  const int AGG_G = CDIV(N, 4); // 4 waves/block x 1 node/wave

  // ---- layer 1: mm x->buf0, agg(+relu) buf0->buf1 ----
  k_mm_mfma<false, false><<<MMG, B, 0, stream>>>(x, W1, nullptr, buf0, N);
  k_agg<true><<<AGG_G, B, 0, stream>>>(buf0, dinv, row_ptr, cn, b1, buf1, N);
  // ---- layer 2 ----
  k_mm_mfma<false, false><<<MMG, B, 0, stream>>>(buf1, W2, nullptr, buf0, N);
  k_agg<true><<<AGG_G, B, 0, stream>>>(buf0, dinv, row_ptr, cn, b2, buf1, N);
  // ---- layer 3 ----
  k_mm_mfma<false, false><<<MMG, B, 0, stream>>>(buf1, W3, nullptr, buf0, N);
  k_agg<true><<<AGG_G, B, 0, stream>>>(buf0, dinv, row_ptr, cn, b3, buf1, N);
  // ---- MLP head: mm(+bias+relu) buf1->buf0, mm(+bias) buf0->out ----
  k_mm_mfma<true, true><<<MMG, B, 0, stream>>>(buf1, fw1, fb1, buf0, N);
  k_mm_mfma<false, true><<<MMG, B, 0, stream>>>(buf0, fw2, fb2, out, N);
}

// Round 5
// 396.789 us; speedup vs baseline: 1.6421x; 1.0442x over previous
//
#include <hip/hip_runtime.h>
#include <cstdint>
#include <cstddef>

// GCN link prediction: 3x GCNConv(64->64) + ReLU, then 2-layer MLP head.
// N=100k, E=1M, dims 64. CSR built per launch; edges packed int2{src,norm}.
// Round 5: mm occupancy fix (1 tile/wave, launch_bounds(256,4)) + cheaper
// trunc-lo split; agg prefetches the next edge record to overlap the index
// load with the row gather.

#define CDIV(a, b) (((a) + (b) - 1) / (b))
static constexpr int SCAN_B = 1024;

typedef __attribute__((ext_vector_type(8))) short bf16x8;
typedef __attribute__((ext_vector_type(4))) float f32x4;

// Split a into hi (RNE bf16) + lo (truncated bf16 of exact residual).
// |a - (hi+lo)| <= 2^-17 |a| roughly; missing lo*lo MFMA term ~2^-18.
__device__ __forceinline__ void split_bf(float a, short& hi, short& lo) {
  unsigned u = __float_as_uint(a);
  unsigned r = u + (0x7FFF + ((u >> 16) & 1));  // RNE round to bf16
  hi = (short)(r >> 16);
  float hirec = __uint_as_float(r & 0xFFFF0000u);
  float res = a - hirec;  // exact
  lo = (short)(__float_as_uint(res) >> 16);  // truncate
}

__global__ void k_zero_i32(int* __restrict__ p, int n) {
  int i = blockIdx.x * blockDim.x + threadIdx.x;
  if (i < n) p[i] = 0;
}

__global__ void k_count(const int* __restrict__ ei, int* __restrict__ counts, int E) {
  int e = blockIdx.x * blockDim.x + threadIdx.x;
  if (e < E) atomicAdd(&counts[ei[E + e]], 1);
}

__global__ void k_dinv(const int* __restrict__ counts, float* __restrict__ dinv, int n) {
  int i = blockIdx.x * blockDim.x + threadIdx.x;
  if (i < n) dinv[i] = rsqrtf((float)counts[i] + 1.0f);
}

// Inclusive block scan (Hillis-Steele) -> exclusive output + per-block sums.
__global__ void k_scan1(const int* __restrict__ counts, int* __restrict__ excl,
                        int* __restrict__ bsums, int n) {
  __shared__ int sh[SCAN_B];
  int t = threadIdx.x;
  int idx = blockIdx.x * SCAN_B + t;
  int v = (idx < n) ? counts[idx] : 0;
  int val = v;
  sh[t] = val;
  __syncthreads();
  for (int off = 1; off < SCAN_B; off <<= 1) {
    int add = (t >= off) ? sh[t - off] : 0;
    __syncthreads();
    val += add;
    sh[t] = val;
    __syncthreads();
  }
  if (idx < n) excl[idx] = val - v;
  if (t == SCAN_B - 1) bsums[blockIdx.x] = val;
}

__global__ void k_scan2(int* __restrict__ bsums, int nb) {
  __shared__ int sh[SCAN_B];
  int t = threadIdx.x;
  int v = (t < nb) ? bsums[t] : 0;
  int val = v;
  sh[t] = val;
  __syncthreads();
  for (int off = 1; off < SCAN_B; off <<= 1) {
    int add = (t >= off) ? sh[t - off] : 0;
    __syncthreads();
    val += add;
    sh[t] = val;
    __syncthreads();
  }
  if (t < nb) bsums[t] = val - v;
}

__global__ void k_scan3(int* __restrict__ row_ptr, const int* __restrict__ bsums,
                        int* __restrict__ counts, int n, int E) {
  int i = blockIdx.x * blockDim.x + threadIdx.x;
  if (i < n) {
    row_ptr[i] += bsums[i >> 10];  // SCAN_B == 1024
    counts[i] = 0;                 // reuse as fill cursors
  }
  if (i == 0) row_ptr[n] = E;
}

__global__ void k_fill(const int* __restrict__ ei, const float* __restrict__ dinv,
                       const int* __restrict__ row_ptr, int* __restrict__ counts,
                       int2* __restrict__ cn, int E) {
  int e = blockIdx.x * blockDim.x + threadIdx.x;
  if (e >= E) return;
  int s = ei[e];
  int d = ei[E + e];
  int pos = row_ptr[d] + atomicAdd(&counts[d], 1);
  cn[pos] = make_int2(s, __float_as_int(dinv[s] * dinv[d]));
}

// C[n x 64] = A[n x 64] @ W[64 x 64] (+bias) (+relu) via split-bf16 MFMA.
// One wave per 16-row tile. Layouts (m89/m120-verified):
//   A frag: A[m=lane&15][k=quad*8+j] (quad=lane>>4), k-tiles of 32.
//   B frag: B[k=quad*8+j][n=lane&15]
//   C frag: col=lane&15, row=quad*4+reg
template <bool RELU_OUT, bool HAS_BIAS>
__global__ __launch_bounds__(256, 4)
void k_mm_mfma(const float* __restrict__ in, const float* __restrict__ W,
               const float* __restrict__ bias, float* __restrict__ out, int n) {
  int lane = threadIdx.x & 63;
  int col = lane & 15, quad = lane >> 4;
  int wid = (blockIdx.x * blockDim.x + threadIdx.x) >> 6;
  int nw = (gridDim.x * blockDim.x) >> 6;
  int ntiles = (n + 15) >> 4;

  // W fragments: 4 col-tiles x 2 k-tiles, hi+lo
  bf16x8 wh[4][2], wl[4][2];
#pragma unroll
  for (int t = 0; t < 4; ++t)
#pragma unroll
    for (int q = 0; q < 2; ++q)
#pragma unroll
      for (int j = 0; j < 8; ++j) {
        int k = q * 32 + quad * 8 + j;
        short hi, lo;
        split_bf(W[k * 64 + t * 16 + col], hi, lo);
        wh[t][q][j] = hi;
        wl[t][q][j] = lo;
      }
  float bv[4];
#pragma unroll
  for (int t = 0; t < 4; ++t) bv[t] = HAS_BIAS ? bias[t * 16 + col] : 0.0f;

  for (int tile = wid; tile < ntiles; tile += nw) {
    int row0 = tile << 4;
    int ar = row0 + col;
    if (ar > n - 1) ar = n - 1;  // clamp (tail tile); stores are guarded
    const float4* arow = (const float4*)(in + (size_t)ar * 64 + quad * 8);
    bf16x8 ah[2], al[2];
#pragma unroll
    for (int q = 0; q < 2; ++q) {
      float4 v0 = arow[q * 8 + 0];
      float4 v1 = arow[q * 8 + 1];
      float av[8] = {v0.x, v0.y, v0.z, v0.w, v1.x, v1.y, v1.z, v1.w};
#pragma unroll
      for (int j = 0; j < 8; ++j) {
        short hi, lo;
        split_bf(av[j], hi, lo);
        ah[q][j] = hi;
        al[q][j] = lo;
      }
    }
    f32x4 acc[4];
#pragma unroll
    for (int t = 0; t < 4; ++t) acc[t] = (f32x4){0.f, 0.f, 0.f, 0.f};
#pragma unroll
    for (int t = 0; t < 4; ++t)
#pragma unroll
      for (int q = 0; q < 2; ++q) {
        acc[t] = __builtin_amdgcn_mfma_f32_16x16x32_bf16(ah[q], wh[t][q], acc[t], 0, 0, 0);
        acc[t] = __builtin_amdgcn_mfma_f32_16x16x32_bf16(ah[q], wl[t][q], acc[t], 0, 0, 0);
        acc[t] = __builtin_amdgcn_mfma_f32_16x16x32_bf16(al[q], wh[t][q], acc[t], 0, 0, 0);
      }
#pragma unroll
    for (int t = 0; t < 4; ++t)
#pragma unroll
      for (int r = 0; r < 4; ++r) {
        int row = row0 + quad * 4 + r;
        if (row < n) {
          float v = acc[t][r] + bv[t];
          if (RELU_OUT) v = fmaxf(v, 0.0f);
          out[(size_t)row * 64 + t * 16 + col] = v;
        }
      }
  }
}

// One wave per node; 4 edge-slots x 16 lanes x float4; next-edge prefetch.
template <bool RELU>
__global__ void k_agg(const float* __restrict__ hw, const float* __restrict__ dinv,
                      const int* __restrict__ row_ptr, const int2* __restrict__ cn,
                      const float* __restrict__ bias, float* __restrict__ out, int n) {
  int wid = (blockIdx.x * blockDim.x + threadIdx.x) >> 6;
  if (wid >= n) return;
  int lane = threadIdx.x & 63;
  int slot = lane >> 4;  // 0..3
  int fg = lane & 15;    // float4 feature group
  const float4* hw4 = (const float4*)hw;

  int p0 = row_ptr[wid], p1 = row_ptr[wid + 1];
  float4 acc = make_float4(0.f, 0.f, 0.f, 0.f);
  int p = p0 + slot;
  int2 e = (p < p1) ? cn[p] : make_int2(0, 0);  // norm 0 -> no contribution
  while (p < p1) {
    int pn = p + 4;
    int2 en = (pn < p1) ? cn[pn] : make_int2(0, 0);  // prefetch next record
    float nrm = __int_as_float(e.y);
    float4 v = hw4[(size_t)e.x * 16 + fg];
    acc.x = fmaf(v.x, nrm, acc.x);
    acc.y = fmaf(v.y, nrm, acc.y);
    acc.z = fmaf(v.z, nrm, acc.z);
    acc.w = fmaf(v.w, nrm, acc.w);
    e = en;
    p = pn;
  }
#pragma unroll
  for (int off = 16; off < 64; off <<= 1) {
    acc.x += __shfl_xor(acc.x, off);
    acc.y += __shfl_xor(acc.y, off);
    acc.z += __shfl_xor(acc.z, off);
    acc.w += __shfl_xor(acc.w, off);
  }
  if (slot == 0) {
    float di = dinv[wid];
    float d2 = di * di;
    float4 self = hw4[(size_t)wid * 16 + fg];
    float4 b4 = ((const float4*)bias)[fg];
    float4 r;
    r.x = fmaf(self.x, d2, acc.x + b4.x);
    r.y = fmaf(self.y, d2, acc.y + b4.y);
    r.z = fmaf(self.z, d2, acc.z + b4.z);
    r.w = fmaf(self.w, d2, acc.w + b4.w);
    if (RELU) {
      r.x = fmaxf(r.x, 0.f); r.y = fmaxf(r.y, 0.f);
      r.z = fmaxf(r.z, 0.f); r.w = fmaxf(r.w, 0.f);
    }
    ((float4*)out)[(size_t)wid * 16 + fg] = r;
  }
}

extern "C" void kernel_launch(void* const* d_in, const int* in_sizes, int n_in,
                              void* d_out, int out_size, void* d_ws, size_t ws_size,
                              hipStream_t stream) {
  const float* x = (const float*)d_in[0];
  const int* ei = (const int*)d_in[1];  // int32 per harness convention
  const float* W1 = (const float*)d_in[2];
  const float* b1 = (const float*)d_in[3];
  const float* W2 = (const float*)d_in[4];
  const float* b2 = (const float*)d_in[5];
  const float* W3 = (const float*)d_in[6];
  const float* b3 = (const float*)d_in[7];
  const float* fw1 = (const float*)d_in[8];
  const float* fb1 = (const float*)d_in[9];
  const float* fw2 = (const float*)d_in[10];
  const float* fb2 = (const float*)d_in[11];
  float* out = (float*)d_out;

  const int N = in_sizes[0] / 64;
  const int E = in_sizes[1] / 2;

  // workspace carve-up (~35 MB); d_out is the second activation buffer
  char* w = (char*)d_ws;
  auto take = [&](size_t bytes) -> char* {
    char* p = w;
    w += (bytes + 255) & ~(size_t)255;
    return p;
  };
  float* dinv = (float*)take((size_t)N * 4);
  int* counts = (int*)take((size_t)N * 4);
  int* row_ptr = (int*)take((size_t)(N + 1) * 4);
  int* bsums = (int*)take((size_t)SCAN_B * 4);
  int2* cn = (int2*)take((size_t)E * 8);
  float* buf0 = (float*)take((size_t)N * 64 * 4);
  float* buf1 = out;  // alias d_out as ping-pong buffer (rewritten at the end)

  const int B = 256;
  const int nb_scan = CDIV(N, SCAN_B);

  // ---- CSR build + degrees ----
  k_zero_i32<<<CDIV(N, B), B, 0, stream>>>(counts, N);
  k_count<<<CDIV(E, B), B, 0, stream>>>(ei, counts, E);
  k_dinv<<<CDIV(N, B), B, 0, stream>>>(counts, dinv, N);
  k_scan1<<<nb_scan, SCAN_B, 0, stream>>>(counts, row_ptr, bsums, N);
  k_scan2<<<1, SCAN_B, 0, stream>>>(bsums, nb_scan);
  k_scan3<<<CDIV(N, B), B, 0, stream>>>(row_ptr, bsums, counts, N, E);
  k_fill<<<CDIV(E, B), B, 0, stream>>>(ei, dinv, row_ptr, counts, cn, E);

  const int ntiles = CDIV(N, 16);
  const int MMG = CDIV(ntiles, 4);  // 1 row-tile per wave
  const int AGG_G = CDIV(N, 4);     // 1 node per wave

  // ---- layer 1: mm x->buf0, agg(+relu) buf0->buf1 ----
  k_mm_mfma<false, false><<<MMG, B, 0, stream>>>(x, W1, nullptr, buf0, N);
  k_agg<true><<<AGG_G, B, 0, stream>>>(buf0, dinv, row_ptr, cn, b1, buf1, N);
  // ---- layer 2 ----
  k_mm_mfma<false, false><<<MMG, B, 0, stream>>>(buf1, W2, nullptr, buf0, N);
  k_agg<true><<<AGG_G, B, 0, stream>>>(buf0, dinv, row_ptr, cn, b2, buf1, N);
  // ---- layer 3 ----
  k_mm_mfma<false, false><<<MMG, B, 0, stream>>>(buf1, W3, nullptr, buf0, N);
  k_agg<true><<<AGG_G, B, 0, stream>>>(buf0, dinv, row_ptr, cn, b3, buf1, N);
  // ---- MLP head: mm(+bias+relu) buf1->buf0, mm(+bias) buf0->out ----
  k_mm_mfma<true, true><<<MMG, B, 0, stream>>>(buf1, fw1, fb1, buf0, N);
  k_mm_mfma<false, true><<<MMG, B, 0, stream>>>(buf0, fw2, fb2, out, N);
}

// Round 6
// 395.309 us; speedup vs baseline: 1.6483x; 1.0037x over previous
//
#include <hip/hip_runtime.h>
#include <cstdint>
#include <cstddef>

// GCN link prediction: 3x GCNConv(64->64) + ReLU, then 2-layer MLP head.
// N=100k, E=1M, dims 64. CSR built per launch; edges packed int2{src,norm}.
// Round 6: k_prep pre-splits all 5 weight matrices into hi/lo bf16 in MFMA
// fragment order (80 KB packed, L2-resident). k_mm_mfma loads W frags with
// 16 coalesced 16B loads — no per-wave W conversion, no spill pressure
// (launch_bounds(256,3), live set ~130 VGPRs).

#define CDIV(a, b) (((a) + (b) - 1) / (b))
static constexpr int SCAN_B = 1024;

typedef __attribute__((ext_vector_type(8))) short bf16x8;
typedef __attribute__((ext_vector_type(4))) float f32x4;

// Split a into hi (RNE bf16) + lo (truncated bf16 of exact residual).
__device__ __forceinline__ void split_bf(float a, short& hi, short& lo) {
  unsigned u = __float_as_uint(a);
  unsigned r = u + (0x7FFF + ((u >> 16) & 1));  // RNE round to bf16
  hi = (short)(r >> 16);
  float hirec = __uint_as_float(r & 0xFFFF0000u);
  float res = a - hirec;  // exact
  lo = (short)(__float_as_uint(res) >> 16);  // truncate
}

__global__ void k_zero_i32(int* __restrict__ p, int n) {
  int i = blockIdx.x * blockDim.x + threadIdx.x;
  if (i < n) p[i] = 0;
}

__global__ void k_count(const int* __restrict__ ei, int* __restrict__ counts, int E) {
  int e = blockIdx.x * blockDim.x + threadIdx.x;
  if (e < E) atomicAdd(&counts[ei[E + e]], 1);
}

__global__ void k_dinv(const int* __restrict__ counts, float* __restrict__ dinv, int n) {
  int i = blockIdx.x * blockDim.x + threadIdx.x;
  if (i < n) dinv[i] = rsqrtf((float)counts[i] + 1.0f);
}

// Inclusive block scan (Hillis-Steele) -> exclusive output + per-block sums.
__global__ void k_scan1(const int* __restrict__ counts, int* __restrict__ excl,
                        int* __restrict__ bsums, int n) {
  __shared__ int sh[SCAN_B];
  int t = threadIdx.x;
  int idx = blockIdx.x * SCAN_B + t;
  int v = (idx < n) ? counts[idx] : 0;
  int val = v;
  sh[t] = val;
  __syncthreads();
  for (int off = 1; off < SCAN_B; off <<= 1) {
    int add = (t >= off) ? sh[t - off] : 0;
    __syncthreads();
    val += add;
    sh[t] = val;
    __syncthreads();
  }
  if (idx < n) excl[idx] = val - v;
  if (t == SCAN_B - 1) bsums[blockIdx.x] = val;
}

__global__ void k_scan2(int* __restrict__ bsums, int nb) {
  __shared__ int sh[SCAN_B];
  int t = threadIdx.x;
  int v = (t < nb) ? bsums[t] : 0;
  int val = v;
  sh[t] = val;
  __syncthreads();
  for (int off = 1; off < SCAN_B; off <<= 1) {
    int add = (t >= off) ? sh[t - off] : 0;
    __syncthreads();
    val += add;
    sh[t] = val;
    __syncthreads();
  }
  if (t < nb) bsums[t] = val - v;
}

__global__ void k_scan3(int* __restrict__ row_ptr, const int* __restrict__ bsums,
                        int* __restrict__ counts, int n, int E) {
  int i = blockIdx.x * blockDim.x + threadIdx.x;
  if (i < n) {
    row_ptr[i] += bsums[i >> 10];  // SCAN_B == 1024
    counts[i] = 0;                 // reuse as fill cursors
  }
  if (i == 0) row_ptr[n] = E;
}

__global__ void k_fill(const int* __restrict__ ei, const float* __restrict__ dinv,
                       const int* __restrict__ row_ptr, int* __restrict__ counts,
                       int2* __restrict__ cn, int E) {
  int e = blockIdx.x * blockDim.x + threadIdx.x;
  if (e >= E) return;
  int s = ei[e];
  int d = ei[E + e];
  int pos = row_ptr[d] + atomicAdd(&counts[d], 1);
  cn[pos] = make_int2(s, __float_as_int(dinv[s] * dinv[d]));
}

// Pre-split 5 weight matrices (64x64 each, [in,out] row-major) into hi/lo
// bf16 fragments. Packed layout (bf16x8 units, 16 B each):
//   packed[mat*1024 + ((t*2+q)*2+h)*64 + lane],  lane = quad*16+col
// holding W[(q*32+quad*8+j)*64 + t*16+col] for j=0..7.
// One block per matrix, 512 threads = (t,q,lane).
__global__ void k_prep(const float* __restrict__ w0, const float* __restrict__ w1,
                       const float* __restrict__ w2, const float* __restrict__ w3,
                       const float* __restrict__ w4, bf16x8* __restrict__ packed) {
  const float* W;
  switch (blockIdx.x) {
    case 0: W = w0; break;
    case 1: W = w1; break;
    case 2: W = w2; break;
    case 3: W = w3; break;
    default: W = w4; break;
  }
  int tid = threadIdx.x;            // 0..511
  int lane = tid & 63;
  int q = (tid >> 6) & 1;
  int t = tid >> 7;
  int col = lane & 15, quad = lane >> 4;
  bf16x8 hi8, lo8;
#pragma unroll
  for (int j = 0; j < 8; ++j) {
    int k = q * 32 + quad * 8 + j;
    short hi, lo;
    split_bf(W[k * 64 + t * 16 + col], hi, lo);
    hi8[j] = hi;
    lo8[j] = lo;
  }
  size_t base = (size_t)blockIdx.x * 1024 + ((t * 2 + q) * 2) * 64 + lane;
  packed[base] = hi8;        // h=0
  packed[base + 64] = lo8;   // h=1
}

// C[n x 64] = A[n x 64] @ W[64 x 64] (+bias) (+relu) via split-bf16 MFMA.
// One wave per 16-row tile. W fragments preloaded from packed buffer.
// Layouts (m89/m120-verified): A[m=lane&15][k=quad*8+j]; B[k][n=lane&15];
// C col=lane&15, row=quad*4+reg.
template <bool RELU_OUT, bool HAS_BIAS>
__global__ __launch_bounds__(256, 3)
void k_mm_mfma(const float* __restrict__ in, const bf16x8* __restrict__ Wp,
               const float* __restrict__ bias, float* __restrict__ out, int n) {
  int lane = threadIdx.x & 63;
  int col = lane & 15, quad = lane >> 4;
  int wid = (blockIdx.x * blockDim.x + threadIdx.x) >> 6;
  int nw = (gridDim.x * blockDim.x) >> 6;
  int ntiles = (n + 15) >> 4;

  bf16x8 wh[4][2], wl[4][2];
#pragma unroll
  for (int t = 0; t < 4; ++t)
#pragma unroll
    for (int q = 0; q < 2; ++q) {
      wh[t][q] = Wp[((t * 2 + q) * 2) * 64 + lane];
      wl[t][q] = Wp[((t * 2 + q) * 2 + 1) * 64 + lane];
    }
  float bv[4];
#pragma unroll
  for (int t = 0; t < 4; ++t) bv[t] = HAS_BIAS ? bias[t * 16 + col] : 0.0f;

  for (int tile = wid; tile < ntiles; tile += nw) {
    int row0 = tile << 4;
    int ar = row0 + col;
    if (ar > n - 1) ar = n - 1;  // clamp (tail tile); stores are guarded
    const float4* arow = (const float4*)(in + (size_t)ar * 64 + quad * 8);
    bf16x8 ah[2], al[2];
#pragma unroll
    for (int q = 0; q < 2; ++q) {
      float4 v0 = arow[q * 8 + 0];
      float4 v1 = arow[q * 8 + 1];
      float av[8] = {v0.x, v0.y, v0.z, v0.w, v1.x, v1.y, v1.z, v1.w};
#pragma unroll
      for (int j = 0; j < 8; ++j) {
        short hi, lo;
        split_bf(av[j], hi, lo);
        ah[q][j] = hi;
        al[q][j] = lo;
      }
    }
    f32x4 acc[4];
#pragma unroll
    for (int t = 0; t < 4; ++t) acc[t] = (f32x4){0.f, 0.f, 0.f, 0.f};
#pragma unroll
    for (int t = 0; t < 4; ++t)
#pragma unroll
      for (int q = 0; q < 2; ++q) {
        acc[t] = __builtin_amdgcn_mfma_f32_16x16x32_bf16(ah[q], wh[t][q], acc[t], 0, 0, 0);
        acc[t] = __builtin_amdgcn_mfma_f32_16x16x32_bf16(ah[q], wl[t][q], acc[t], 0, 0, 0);
        acc[t] = __builtin_amdgcn_mfma_f32_16x16x32_bf16(al[q], wh[t][q], acc[t], 0, 0, 0);
      }
#pragma unroll
    for (int t = 0; t < 4; ++t)
#pragma unroll
      for (int r = 0; r < 4; ++r) {
        int row = row0 + quad * 4 + r;
        if (row < n) {
          float v = acc[t][r] + bv[t];
          if (RELU_OUT) v = fmaxf(v, 0.0f);
          out[(size_t)row * 64 + t * 16 + col] = v;
        }
      }
  }
}

// One wave per node; 4 edge-slots x 16 lanes x float4; next-edge prefetch.
template <bool RELU>
__global__ void k_agg(const float* __restrict__ hw, const float* __restrict__ dinv,
                      const int* __restrict__ row_ptr, const int2* __restrict__ cn,
                      const float* __restrict__ bias, float* __restrict__ out, int n) {
  int wid = (blockIdx.x * blockDim.x + threadIdx.x) >> 6;
  if (wid >= n) return;
  int lane = threadIdx.x & 63;
  int slot = lane >> 4;  // 0..3
  int fg = lane & 15;    // float4 feature group
  const float4* hw4 = (const float4*)hw;

  int p0 = row_ptr[wid], p1 = row_ptr[wid + 1];
  float4 acc = make_float4(0.f, 0.f, 0.f, 0.f);
  int p = p0 + slot;
  int2 e = (p < p1) ? cn[p] : make_int2(0, 0);  // norm 0 -> no contribution
  while (p < p1) {
    int pn = p + 4;
    int2 en = (pn < p1) ? cn[pn] : make_int2(0, 0);  // prefetch next record
    float nrm = __int_as_float(e.y);
    float4 v = hw4[(size_t)e.x * 16 + fg];
    acc.x = fmaf(v.x, nrm, acc.x);
    acc.y = fmaf(v.y, nrm, acc.y);
    acc.z = fmaf(v.z, nrm, acc.z);
    acc.w = fmaf(v.w, nrm, acc.w);
    e = en;
    p = pn;
  }
#pragma unroll
  for (int off = 16; off < 64; off <<= 1) {
    acc.x += __shfl_xor(acc.x, off);
    acc.y += __shfl_xor(acc.y, off);
    acc.z += __shfl_xor(acc.z, off);
    acc.w += __shfl_xor(acc.w, off);
  }
  if (slot == 0) {
    float di = dinv[wid];
    float d2 = di * di;
    float4 self = hw4[(size_t)wid * 16 + fg];
    float4 b4 = ((const float4*)bias)[fg];
    float4 r;
    r.x = fmaf(self.x, d2, acc.x + b4.x);
    r.y = fmaf(self.y, d2, acc.y + b4.y);
    r.z = fmaf(self.z, d2, acc.z + b4.z);
    r.w = fmaf(self.w, d2, acc.w + b4.w);
    if (RELU) {
      r.x = fmaxf(r.x, 0.f); r.y = fmaxf(r.y, 0.f);
      r.z = fmaxf(r.z, 0.f); r.w = fmaxf(r.w, 0.f);
    }
    ((float4*)out)[(size_t)wid * 16 + fg] = r;
  }
}

extern "C" void kernel_launch(void* const* d_in, const int* in_sizes, int n_in,
                              void* d_out, int out_size, void* d_ws, size_t ws_size,
                              hipStream_t stream) {
  const float* x = (const float*)d_in[0];
  const int* ei = (const int*)d_in[1];  // int32 per harness convention
  const float* W1 = (const float*)d_in[2];
  const float* b1 = (const float*)d_in[3];
  const float* W2 = (const float*)d_in[4];
  const float* b2 = (const float*)d_in[5];
  const float* W3 = (const float*)d_in[6];
  const float* b3 = (const float*)d_in[7];
  const float* fw1 = (const float*)d_in[8];
  const float* fb1 = (const float*)d_in[9];
  const float* fw2 = (const float*)d_in[10];
  const float* fb2 = (const float*)d_in[11];
  float* out = (float*)d_out;

  const int N = in_sizes[0] / 64;
  const int E = in_sizes[1] / 2;

  // workspace carve-up (~35 MB); d_out is the second activation buffer
  char* w = (char*)d_ws;
  auto take = [&](size_t bytes) -> char* {
    char* p = w;
    w += (bytes + 255) & ~(size_t)255;
    return p;
  };
  float* dinv = (float*)take((size_t)N * 4);
  int* counts = (int*)take((size_t)N * 4);
  int* row_ptr = (int*)take((size_t)(N + 1) * 4);
  int* bsums = (int*)take((size_t)SCAN_B * 4);
  int2* cn = (int2*)take((size_t)E * 8);
  bf16x8* wpack = (bf16x8*)take((size_t)5 * 1024 * 16);  // 80 KB
  float* buf0 = (float*)take((size_t)N * 64 * 4);
  float* buf1 = out;  // alias d_out as ping-pong buffer (rewritten at the end)

  const int B = 256;
  const int nb_scan = CDIV(N, SCAN_B);

  // ---- weight prep + CSR build + degrees ----
  k_prep<<<5, 512, 0, stream>>>(W1, W2, W3, fw1, fw2, wpack);
  k_zero_i32<<<CDIV(N, B), B, 0, stream>>>(counts, N);
  k_count<<<CDIV(E, B), B, 0, stream>>>(ei, counts, E);
  k_dinv<<<CDIV(N, B), B, 0, stream>>>(counts, dinv, N);
  k_scan1<<<nb_scan, SCAN_B, 0, stream>>>(counts, row_ptr, bsums, N);
  k_scan2<<<1, SCAN_B, 0, stream>>>(bsums, nb_scan);
  k_scan3<<<CDIV(N, B), B, 0, stream>>>(row_ptr, bsums, counts, N, E);
  k_fill<<<CDIV(E, B), B, 0, stream>>>(ei, dinv, row_ptr, counts, cn, E);

  const int ntiles = CDIV(N, 16);
  const int MMG = CDIV(ntiles, 4);  // 1 row-tile per wave
  const int AGG_G = CDIV(N, 4);     // 1 node per wave

  // ---- layer 1: mm x->buf0, agg(+relu) buf0->buf1 ----
  k_mm_mfma<false, false><<<MMG, B, 0, stream>>>(x, wpack + 0 * 1024, nullptr, buf0, N);
  k_agg<true><<<AGG_G, B, 0, stream>>>(buf0, dinv, row_ptr, cn, b1, buf1, N);
  // ---- layer 2 ----
  k_mm_mfma<false, false><<<MMG, B, 0, stream>>>(buf1, wpack + 1 * 1024, nullptr, buf0, N);
  k_agg<true><<<AGG_G, B, 0, stream>>>(buf0, dinv, row_ptr, cn, b2, buf1, N);
  // ---- layer 3 ----
  k_mm_mfma<false, false><<<MMG, B, 0, stream>>>(buf1, wpack + 2 * 1024, nullptr, buf0, N);
  k_agg<true><<<AGG_G, B, 0, stream>>>(buf0, dinv, row_ptr, cn, b3, buf1, N);
  // ---- MLP head: mm(+bias+relu) buf1->buf0, mm(+bias) buf0->out ----
  k_mm_mfma<true, true><<<MMG, B, 0, stream>>>(buf1, wpack + 3 * 1024, fb1, buf0, N);
  k_mm_mfma<false, true><<<MMG, B, 0, stream>>>(buf0, wpack + 4 * 1024, fb2, out, N);
}